// Round 17
// baseline (619.009 us; speedup 1.0000x reference)
//
#include <hip/hip_runtime.h>
#include <math.h>

#define N_NODES_C  25000
#define N_EDGES_C  100000
#define N_GRAPHS_C 1000
#define EPB 128   // edges per block in msg_kernel

typedef __attribute__((ext_vector_type(8))) _Float16 f16x8;
typedef __attribute__((ext_vector_type(2))) _Float16 f16x2;
typedef __attribute__((ext_vector_type(4))) float   f32x4;

__device__ __forceinline__ float lrelu(float x) { return x > 0.f ? x : 0.01f * x; }
__device__ __forceinline__ float sigm(float x)  { return 1.f / (1.f + __expf(-x)); }
__device__ __forceinline__ f32x4 MFH(f16x8 a, f16x8 b, f32x4 c) {
  return __builtin_amdgcn_mfma_f32_16x16x32_f16(a, b, c, 0, 0, 0);
}

// ---------------------------------------------------------------- lin0 (LDS-staged weights)
__global__ __launch_bounds__(256) void lin0_kernel(const float* __restrict__ x,
                            const float* __restrict__ w, const float* __restrict__ b,
                            float* __restrict__ nodeF) {
  __shared__ float ws[64 * 15];
  __shared__ float bs[64];
  __shared__ float xr[4][16];
  const int tid = threadIdx.x;
  for (int i = tid; i < 896; i += 256) { int o = i / 14, j = i % 14; ws[o * 15 + j] = w[i]; }
  if (tid < 64) bs[tid] = b[tid];
  const int nl = tid >> 6, o = tid & 63;
  const int n = blockIdx.x * 4 + nl;
  if (o < 14 && n < N_NODES_C) xr[nl][o] = x[n * 14 + o];
  __syncthreads();
  if (n < N_NODES_C) {
    float s = bs[o];
#pragma unroll
    for (int j = 0; j < 14; ++j) s += xr[nl][j] * ws[o * 15 + j];
    nodeF[n * 64 + o] = lrelu(s);
  }
}

// ---------------------------------------------------------------- degree + graph offsets (merged)
__global__ void deg_kernel(const int* __restrict__ ei, const int* __restrict__ batch,
                           float* __restrict__ deg, int* __restrict__ goff) {
  int e = blockIdx.x * blockDim.x + threadIdx.x;
  if (e < N_EDGES_C) atomicAdd(&deg[ei[N_EDGES_C + e]], 1.f);
  if (e <= N_GRAPHS_C) {
    int lo = 0, hi = N_NODES_C;
    while (lo < hi) { int mid = (lo + hi) >> 1; if (batch[mid] < e) lo = mid + 1; else hi = mid; }
    goff[e] = lo;
  }
}

__global__ void invdeg_kernel(float* __restrict__ deg) {
  int n = blockIdx.x * blockDim.x + threadIdx.x;
  if (n < N_NODES_C) { float v = deg[n]; deg[n] = v > 0.f ? 1.f / v : 0.f; }
}

// ---------------------------------------------------------------- all weight prep (merged)
// Wp[i]: i = ((((d*2 + p)*2 + kci)*4 + obq)*64 + lane)*8 + j
//   o = obq*16+(lane&15), h = (p*2+kci)*32+(lane>>4)*8+j, value = W2[(d*64+o)*128+h]
//   -> 4 obq frags contiguous (1024 B apart) per (d,p,kci).
// B2p[i]: i = ((obq*2+kc2)*64+lane)*8+j ; o as above, d = kc2*32+(lane>>4)*8+j
__global__ __launch_bounds__(256) void prep_kernel(
    const float* __restrict__ net_w2, const float* __restrict__ net_b2,
    const float* __restrict__ conv_root,
    const float* __restrict__ w_ih, const float* __restrict__ w_hh,
    _Float16* __restrict__ Wp, _Float16* __restrict__ B2p,
    _Float16* __restrict__ Rtp, _Float16* __restrict__ Wip, _Float16* __restrict__ Whp) {
  int i = blockIdx.x * 256 + threadIdx.x;  // < 524288
  {
    int j = i & 7, lane = (i >> 3) & 63, obq = (i >> 9) & 3, kci = (i >> 11) & 1;
    int p = (i >> 12) & 1, d = i >> 13;
    int col = lane & 15, kg = lane >> 4;
    int o = obq * 16 + col, h = (p * 2 + kci) * 32 + kg * 8 + j;
    Wp[i] = (_Float16)net_w2[((size_t)d * 64 + o) * 128 + h];
  }
  if (i < 4096) {
    int j = i & 7, lane = (i >> 3) & 63, kc2 = (i >> 9) & 1, obq = (i >> 10) & 3;
    int col = lane & 15, kg = lane >> 4;
    int o = obq * 16 + col, d = kc2 * 32 + kg * 8 + j;
    B2p[i] = (_Float16)net_b2[d * 64 + o];
  }
  if (i < 12288) {
    int j = i & 7, lane = (i >> 3) & 63, kc = (i >> 9) & 1, t = i >> 10;
    int o = t * 16 + (lane & 15), d = kc * 32 + (lane >> 4) * 8 + j;
    if (i < 4096) Rtp[i] = (_Float16)conv_root[d * 64 + o];  // B[o,d] = root[d,o]
    Wip[i] = (_Float16)w_ih[o * 64 + d];
    Whp[i] = (_Float16)w_hh[o * 64 + d];
  }
}

// ---------------------------------------------------------------- NNConv message + scatter
// msg = U @ W'^T + x @ B2,  U[e,d*128+h] = x[e,d]*A[e,h]  (fp16 in / fp32 acc)
// Block = 4 waves x 256 threads; wave tile = 32 edges x 64 outputs (o-wide).
// Per d: one U-frag feeds 4 MFMA -> U-build VALU halved (18 vs 36 per 16 MFMA).
// Counted vmcnt(8) + sched_barrier, depth-2 pipeline (2 ISSUEs of 4 frags per d).
__global__ __launch_bounds__(256, 3) void msg_kernel(
    const float* __restrict__ nodef,     // [N,64]
    const int*   __restrict__ ei,        // [2,E]
    const float* __restrict__ eattr,     // [E,4]
    const float* __restrict__ net_w1,    // [128,4]
    const float* __restrict__ net_b1,    // [128]
    const _Float16* __restrict__ Wp,     // frag-major W2 fp16 (1 MB)
    const _Float16* __restrict__ B2p,    // frag-major b2 fp16 (8 KB)
    float* __restrict__ aggr)            // [N,64]
{
  __shared__ _Float16 xsT[EPB * 64];   // 16 KB  xsT[e][d ^ ((e&7)<<3)]
  __shared__ float    w1s[128 * 5];    // 2.5 KB (w0..w3, b1) per hidden unit

  const int tid = threadIdx.x;         // 0..255
  const int e0 = blockIdx.x * EPB;

  // ---- stage W1+b1
  if (tid < 128) {
    float4 wv = *(const float4*)(net_w1 + tid * 4);
    w1s[tid * 5 + 0] = wv.x; w1s[tid * 5 + 1] = wv.y;
    w1s[tid * 5 + 2] = wv.z; w1s[tid * 5 + 3] = wv.w;
    w1s[tid * 5 + 4] = net_b1[tid];
  }
  // ---- stage x: xsT[e][d] (fp16, swizzled), 2 threads/edge
  {
    const int e = tid >> 1, dh = (tid & 1) * 32;
    int ge = e0 + e;
    const int esw = (e & 7) << 3;
#pragma unroll
    for (int jb = 0; jb < 4; ++jb) {
      int d = dh + jb * 8;
      float4 v0, v1;
      if (ge < N_EDGES_C) {
        const float4* nf4 = (const float4*)(nodef + (size_t)ei[ge] * 64 + d);
        v0 = nf4[0]; v1 = nf4[1];
      } else {
        v0 = make_float4(0.f, 0.f, 0.f, 0.f); v1 = v0;
      }
      f16x8 pk;
      pk[0] = (_Float16)v0.x; pk[1] = (_Float16)v0.y; pk[2] = (_Float16)v0.z; pk[3] = (_Float16)v0.w;
      pk[4] = (_Float16)v1.x; pk[5] = (_Float16)v1.y; pk[6] = (_Float16)v1.z; pk[7] = (_Float16)v1.w;
      *(f16x8*)&xsT[e * 64 + (d ^ esw)] = pk;
    }
  }

  const int lane = tid & 63, wv = tid >> 6;
  const int e0w = wv * 32;             // wave edge base (32 edges/wave)
  const int col = lane & 15;
  const int kg  = lane >> 4;
  const int swz = (col & 7) << 3;

  __syncthreads();  // staging done; rest of kernel is LDS read-only

  // ---- acc init: x @ B2 (16 MFMA)
  f32x4 acc[2][4];
#pragma unroll
  for (int eb = 0; eb < 2; ++eb)
#pragma unroll
    for (int obq = 0; obq < 4; ++obq) acc[eb][obq] = 0.f;
#pragma unroll
  for (int kc2 = 0; kc2 < 2; ++kc2) {
    f16x8 xf[2];
#pragma unroll
    for (int eb = 0; eb < 2; ++eb)
      xf[eb] = *(const f16x8*)&xsT[(e0w + eb * 16 + col) * 64 + ((kc2 * 32 + kg * 8) ^ swz)];
#pragma unroll
    for (int obq = 0; obq < 4; ++obq) {
      f16x8 b2f = *(const f16x8*)(B2p + (obq * 2 + kc2) * 512 + lane * 8);
#pragma unroll
      for (int eb = 0; eb < 2; ++eb) acc[eb][obq] = MFH(xf[eb], b2f, acc[eb][obq]);
    }
  }

  // ---- eattr hoisted once
  float4 at[2];
#pragma unroll
  for (int eb = 0; eb < 2; ++eb) {
    int ge = e0 + e0w + eb * 16 + col;
    at[eb] = (ge < N_EDGES_C) ? *(const float4*)(eattr + (size_t)ge * 4)
                              : make_float4(0.f, 0.f, 0.f, 0.f);
  }

#define ISSUE(BUF, ADDR)                                                  \
  asm volatile("global_load_dwordx4 %0, %4, off\n\t"                      \
               "global_load_dwordx4 %1, %4, off offset:1024\n\t"          \
               "global_load_dwordx4 %2, %4, off offset:2048\n\t"          \
               "global_load_dwordx4 %3, %4, off offset:3072"              \
               : "=&v"((BUF)[0]), "=&v"((BUF)[1]), "=&v"((BUF)[2]), "=&v"((BUF)[3]) \
               : "v"(ADDR)                                                \
               : "memory")
#define COMPUTE(BUF, XV, J)                                               \
  {                                                                       \
    _Pragma("unroll")                                                     \
    for (int eb = 0; eb < 2; ++eb) {                                      \
      unsigned dw = XV[eb].u[(J) >> 1];                                   \
      unsigned xd = __builtin_amdgcn_perm(dw, dw, ((J) & 1) ? 0x03020302u : 0x01000100u); \
      f16x2 x2; { union { unsigned u; f16x2 h; } c; c.u = xd; x2 = c.h; } \
      _Pragma("unroll")                                                   \
      for (int kci = 0; kci < 2; ++kci) {                                 \
        union { f16x8 v; f16x2 pp[4]; } af, Uu;                           \
        af.v = Af[eb][kci];                                               \
        _Pragma("unroll")                                                 \
        for (int q = 0; q < 4; ++q) Uu.pp[q] = af.pp[q] * x2;             \
        acc[eb][0] = MFH(Uu.v, (BUF)[kci * 4 + 0], acc[eb][0]);           \
        acc[eb][1] = MFH(Uu.v, (BUF)[kci * 4 + 1], acc[eb][1]);           \
        acc[eb][2] = MFH(Uu.v, (BUF)[kci * 4 + 2], acc[eb][2]);           \
        acc[eb][3] = MFH(Uu.v, (BUF)[kci * 4 + 3], acc[eb][3]);           \
      }                                                                   \
    }                                                                     \
  }

  // ---- 2 passes over kc-halves; per pass: 4 A-frags, pipelined d-loop (depth 2)
  // Wp strides (halfs): p 4096, kci 2048, d 8192.
  const _Float16* wp_base = Wp + lane * 8;
#pragma unroll 1
  for (int p = 0; p < 2; ++p) {
    f16x8 Af[2][2];
#pragma unroll
    for (int kci = 0; kci < 2; ++kci) {
      float4 wr[8]; float wb[8];
#pragma unroll
      for (int j = 0; j < 8; ++j) {
        int hq = (p * 2 + kci) * 32 + kg * 8 + j;
        wr[j] = *(const float4*)&w1s[hq * 5];
        wb[j] = w1s[hq * 5 + 4];
      }
#pragma unroll
      for (int eb = 0; eb < 2; ++eb) {
        f16x8 F;
#pragma unroll
        for (int j = 0; j < 8; ++j) {
          float a = wb[j] + at[eb].x * wr[j].x + at[eb].y * wr[j].y
                          + at[eb].z * wr[j].z + at[eb].w * wr[j].w;
          F[j] = (_Float16)lrelu(a);
        }
        Af[eb][kci] = F;
      }
    }

    const _Float16* wp_p = wp_base + p * 4096;
    f16x8 B0[8], B1[8];
    ISSUE(B0 + 0, wp_p);                 // d=0 kci=0
    ISSUE(B0 + 4, wp_p + 2048);          // d=0 kci=1
    ISSUE(B1 + 0, wp_p + 8192);          // d=1 kci=0
    ISSUE(B1 + 4, wp_p + 8192 + 2048);   // d=1 kci=1

#pragma unroll 1
    for (int d8 = 0; d8 < 64; d8 += 8) {
      union XU { f16x8 v; unsigned u[4]; };
      XU XV[2];
#pragma unroll
      for (int eb = 0; eb < 2; ++eb)
        XV[eb].v = *(const f16x8*)&xsT[(e0w + eb * 16 + col) * 64 + (d8 ^ swz)];
#pragma unroll
      for (int j = 0; j < 8; ++j) {
        const int d = d8 + j;
        if (d < 63) { asm volatile("s_waitcnt vmcnt(8)"); }  // d's 8 done; d+1 in flight
        else        { asm volatile("s_waitcnt vmcnt(0)"); }  // last d: drain
        __builtin_amdgcn_sched_barrier(0);                    // rule #18
        if ((j & 1) == 0) { COMPUTE(B0, XV, j); } else { COMPUTE(B1, XV, j); }
        __builtin_amdgcn_sched_barrier(0);
        if (d < 62) {
          const _Float16* adr = wp_p + (size_t)(d + 2) * 8192;
          if ((j & 1) == 0) { ISSUE(B0 + 0, adr); ISSUE(B0 + 4, adr + 2048); }
          else              { ISSUE(B1 + 0, adr); ISSUE(B1 + 4, adr + 2048); }
        }
      }
    }
  }
#undef ISSUE
#undef COMPUTE

  // ---- scatter-add into aggr[dst] (full 64-o rows per edge)
#pragma unroll
  for (int eb = 0; eb < 2; ++eb) {
#pragma unroll
    for (int r = 0; r < 4; ++r) {
      int e = e0w + eb * 16 + kg * 4 + r;
      int ge = e0 + e;
      if (ge < N_EDGES_C) {
        int dn = ei[N_EDGES_C + ge];
#pragma unroll
        for (int obq = 0; obq < 4; ++obq)
          atomicAdd(&aggr[(size_t)dn * 64 + obq * 16 + col], acc[eb][obq][r]);
      }
    }
  }
}

// ---------------------------------------------------------------- root matmul + GRU (fp16 MFMA)
// Block: 32 nodes, 2 waves x 16 nodes; aggr reads hoisted before Phase-1 MFMA.
__global__ __launch_bounds__(128) void node_update_kernel(
    float* __restrict__ aggr, const float* __restrict__ invdeg,
    const _Float16* __restrict__ Rtp, const _Float16* __restrict__ Wip,
    const _Float16* __restrict__ Whp,
    const float* __restrict__ conv_bias,
    const float* __restrict__ b_ih, const float* __restrict__ b_hh,
    float* __restrict__ nodeF)
{
  __shared__ _Float16 ms[2][16 * 64];

  const int tid = threadIdx.x, lane = tid & 63, wv = tid >> 6;
  const int col = lane & 15, kg = lane >> 4;
  const int nwb = blockIdx.x * 32 + wv * 16;

  float invd[4]; int nrow[4];
#pragma unroll
  for (int r = 0; r < 4; ++r) {
    int nn = nwb + kg * 4 + r; nrow[r] = nn;
    invd[r] = (nn < N_NODES_C) ? invdeg[nn] : 0.f;
  }
  float ag[4][4];
#pragma unroll
  for (int t = 0; t < 4; ++t)
#pragma unroll
    for (int r = 0; r < 4; ++r) {
      int nn = nrow[r];
      ag[t][r] = (nn < N_NODES_C) ? aggr[(size_t)nn * 64 + t * 16 + col] : 0.f;
    }

  int arow = nwb + col; if (arow >= N_NODES_C) arow = N_NODES_C - 1;
  f16x8 nf[2];
#pragma unroll
  for (int kc = 0; kc < 2; ++kc) {
    f32x4 v0 = *(const f32x4*)(nodeF + (size_t)arow * 64 + kc * 32 + kg * 8);
    f32x4 v1 = *(const f32x4*)(nodeF + (size_t)arow * 64 + kc * 32 + kg * 8 + 4);
    f16x8 F;
#pragma unroll
    for (int j = 0; j < 4; ++j) { F[j] = (_Float16)v0[j]; F[4 + j] = (_Float16)v1[j]; }
    nf[kc] = F;
  }

  f32x4 racc[4];
#pragma unroll
  for (int t = 0; t < 4; ++t) racc[t] = conv_bias[t * 16 + col];
#pragma unroll
  for (int t = 0; t < 4; ++t)
#pragma unroll
    for (int kc = 0; kc < 2; ++kc)
      racc[t] = MFH(nf[kc], *(const f16x8*)(Rtp + t * 1024 + kc * 512 + lane * 8), racc[t]);

#pragma unroll
  for (int t = 0; t < 4; ++t) {
#pragma unroll
    for (int r = 0; r < 4; ++r) {
      int nn = nrow[r];
      if (nn < N_NODES_C) aggr[(size_t)nn * 64 + t * 16 + col] = 0.f;  // re-zero
      float mval = lrelu(ag[t][r] * invd[r] + racc[t][r]);
      int nl = kg * 4 + r;
      int dsw = (t * 16 + col) ^ ((nl & 7) << 3);
      ms[wv][nl * 64 + dsw] = (_Float16)mval;
    }
  }
  __syncthreads();

  f16x8 ma[2];
#pragma unroll
  for (int kc = 0; kc < 2; ++kc)
    ma[kc] = *(const f16x8*)&ms[wv][col * 64 + ((kc * 32 + kg * 8) ^ ((col & 7) << 3))];

  f32x4 gi[12], gh[12];
#pragma unroll
  for (int t = 0; t < 12; ++t) { gi[t] = b_ih[t * 16 + col]; gh[t] = b_hh[t * 16 + col]; }
#pragma unroll
  for (int t = 0; t < 12; ++t)
#pragma unroll
    for (int kc = 0; kc < 2; ++kc) {
      gi[t] = MFH(ma[kc], *(const f16x8*)(Wip + t * 1024 + kc * 512 + lane * 8), gi[t]);
      gh[t] = MFH(nf[kc], *(const f16x8*)(Whp + t * 1024 + kc * 512 + lane * 8), gh[t]);
    }

#pragma unroll
  for (int t = 0; t < 4; ++t) {
#pragma unroll
    for (int r = 0; r < 4; ++r) {
      int nn = nrow[r];
      if (nn >= N_NODES_C) continue;
      size_t idx = (size_t)nn * 64 + t * 16 + col;
      float hv = nodeF[idx];
      float rr = sigm(gi[t][r] + gh[t][r]);
      float zz = sigm(gi[t + 4][r] + gh[t + 4][r]);
      float nv = tanhf(gi[t + 8][r] + rr * gh[t + 8][r]);
      nodeF[idx] = (1.f - zz) * nv + zz * hv;
    }
  }
}

// ---------------------------------------------------------------- fused Set2Set (3 steps) + final linear
// 256 threads: LSTM gate-per-thread, attention 4 rows/iter (R15 form).
__global__ __launch_bounds__(256) void set2set_kernel(
    const float* __restrict__ nodeF, const int* __restrict__ goff,
    const float* __restrict__ w_ih, const float* __restrict__ w_hh,
    const float* __restrict__ b_ih, const float* __restrict__ b_hh,
    const float* __restrict__ lw, const float* __restrict__ lb,
    float* __restrict__ ebuf, float* __restrict__ dout)
{
  const int g = blockIdx.x, tid = threadIdx.x;
  const int t = tid & 63, grp = tid >> 6;
  __shared__ float qs[128], hs[64], cls[64], gvs[4][64], red[4][64], scal[8];
  if (tid < 128) qs[tid] = 0.f;
  if (tid < 64) { hs[tid] = 0.f; cls[tid] = 0.f; }
  const int s0 = goff[g], s1 = goff[g + 1];
  __syncthreads();

  for (int step = 0; step < 3; ++step) {
    {
      float s = b_ih[grp * 64 + t] + b_hh[grp * 64 + t];
      const float4* wi4 = (const float4*)(w_ih + (grp * 64 + t) * 128);
#pragma unroll 8
      for (int j = 0; j < 32; ++j) {
        float4 w = wi4[j];
        s += qs[4 * j] * w.x + qs[4 * j + 1] * w.y + qs[4 * j + 2] * w.z + qs[4 * j + 3] * w.w;
      }
      const float4* wh4 = (const float4*)(w_hh + (grp * 64 + t) * 64);
#pragma unroll 8
      for (int j = 0; j < 16; ++j) {
        float4 w = wh4[j];
        s += hs[4 * j] * w.x + hs[4 * j + 1] * w.y + hs[4 * j + 2] * w.z + hs[4 * j + 3] * w.w;
      }
      gvs[grp][t] = s;
    }
    __syncthreads();
    if (tid < 64) {
      float c = sigm(gvs[1][t]) * cls[t] + sigm(gvs[0][t]) * tanhf(gvs[2][t]);
      float hn = sigm(gvs[3][t]) * tanhf(c);
      cls[t] = c; hs[t] = hn; qs[t] = hn;
    }
    __syncthreads();
    const float qv = hs[t];

    float emax = -3.0e38f;
    for (int n = s0 + grp; n < s1; n += 4) {
      float p = nodeF[(size_t)n * 64 + t] * qv;
#pragma unroll
      for (int off = 32; off > 0; off >>= 1) p += __shfl_down(p, off);
      float en = __shfl(p, 0);
      if (t == 0) ebuf[n] = en;
      emax = fmaxf(emax, en);
    }
    if (t == 0) scal[grp] = emax;
    __syncthreads();
    emax = fmaxf(fmaxf(scal[0], scal[1]), fmaxf(scal[2], scal[3]));

    float lsum = 0.f;
    for (int n = s0 + tid; n < s1; n += 256) {
      float ex = __expf(ebuf[n] - emax);
      ebuf[n] = ex;
      lsum += ex;
    }
#pragma unroll
    for (int off = 32; off > 0; off >>= 1) lsum += __shfl_down(lsum, off);
    if (t == 0) scal[4 + grp] = lsum;
    __syncthreads();
    float denom = scal[4] + scal[5] + scal[6] + scal[7];

    float r = 0.f;
    for (int n = s0 + grp; n < s1; n += 4) r += ebuf[n] * nodeF[(size_t)n * 64 + t];
    red[grp][t] = r;
    __syncthreads();
    if (tid < 64) {
      float rr = red[0][t] + red[1][t] + red[2][t] + red[3][t];
      qs[64 + t] = (s1 > s0) ? rr / denom : 0.f;
    }
    __syncthreads();
  }
  float sacc = (tid < 128) ? qs[tid] * lw[tid] : 0.f;
#pragma unroll
  for (int off = 32; off > 0; off >>= 1) sacc += __shfl_down(sacc, off);
  if (t == 0) scal[grp] = sacc;
  __syncthreads();
  if (tid == 0) dout[g] = scal[0] + scal[1] + lb[0];
}

// ---------------------------------------------------------------- launch
extern "C" void kernel_launch(void* const* d_in, const int* in_sizes, int n_in,
                              void* d_out, int out_size, void* d_ws, size_t ws_size,
                              hipStream_t stream) {
  const float* x         = (const float*)d_in[0];
  const int*   ei        = (const int*)  d_in[1];
  const float* eattr     = (const float*)d_in[2];
  const int*   batch     = (const int*)  d_in[3];
  const float* lin0_w    = (const float*)d_in[4];
  const float* lin0_b    = (const float*)d_in[5];
  const float* net_w1    = (const float*)d_in[6];
  const float* net_b1    = (const float*)d_in[7];
  const float* net_w2    = (const float*)d_in[8];
  const float* net_b2    = (const float*)d_in[9];
  const float* conv_root = (const float*)d_in[10];
  const float* conv_bias = (const float*)d_in[11];
  const float* gru_w_ih  = (const float*)d_in[12];
  const float* gru_w_hh  = (const float*)d_in[13];
  const float* gru_b_ih  = (const float*)d_in[14];
  const float* gru_b_hh  = (const float*)d_in[15];
  const float* lstm_w_ih = (const float*)d_in[16];
  const float* lstm_w_hh = (const float*)d_in[17];
  const float* lstm_b_ih = (const float*)d_in[18];
  const float* lstm_b_hh = (const float*)d_in[19];
  const float* lin_w     = (const float*)d_in[20];
  const float* lin_b     = (const float*)d_in[21];

  // workspace layout (~13.1 MB)
  float* ws    = (float*)d_ws;
  float* nodeF = ws;                         // 1,600,000 f
  float* aggr  = nodeF + 1600000;            // 1,600,000 f
  float* deg   = aggr + 1600000;             //    25,000 f
  float* ebuf  = deg + 25000;                //    25,000 f
  int*   goff  = (int*)(ebuf + 25000);       //     1,024 i
  _Float16* Rtp = (_Float16*)(goff + 1024);  //     4,096 h
  _Float16* Wip = Rtp + 4096;                //    12,288 h
  _Float16* Whp = Wip + 12288;               //    12,288 h
  _Float16* Wp  = Whp + 12288;               //   524,288 h
  _Float16* B2p = Wp + 524288;               //     4,096 h

  hipMemsetAsync(deg, 0, 25000 * sizeof(float), stream);
  hipMemsetAsync(aggr, 0, 1600000 * sizeof(float), stream);  // node_update re-zeroes thereafter

  lin0_kernel<<<(N_NODES_C + 3) / 4, 256, 0, stream>>>(x, lin0_w, lin0_b, nodeF);
  deg_kernel<<<(N_EDGES_C + 255) / 256, 256, 0, stream>>>(ei, batch, deg, goff);
  invdeg_kernel<<<(N_NODES_C + 255) / 256, 256, 0, stream>>>(deg);
  prep_kernel<<<2048, 256, 0, stream>>>(net_w2, net_b2, conv_root, gru_w_ih, gru_w_hh,
                                        Wp, B2p, Rtp, Wip, Whp);

  for (int step = 0; step < 3; ++step) {
    msg_kernel<<<(N_EDGES_C + EPB - 1) / EPB, 256, 0, stream>>>(
        nodeF, ei, eattr, net_w1, net_b1, Wp, B2p, aggr);
    node_update_kernel<<<(N_NODES_C + 31) / 32, 128, 0, stream>>>(
        aggr, deg, Rtp, Wip, Whp, conv_bias, gru_b_ih, gru_b_hh, nodeF);
  }

  set2set_kernel<<<N_GRAPHS_C, 256, 0, stream>>>(
      nodeF, goff, lstm_w_ih, lstm_w_hh, lstm_b_ih, lstm_b_hh, lin_w, lin_b, ebuf, (float*)d_out);
}

// Round 18
// 564.045 us; speedup vs baseline: 1.0974x; 1.0974x over previous
//
#include <hip/hip_runtime.h>
#include <math.h>

#define N_NODES_C  25000
#define N_EDGES_C  100000
#define N_GRAPHS_C 1000
#define EPB 128   // edges per block in msg_kernel

typedef __attribute__((ext_vector_type(8))) _Float16 f16x8;
typedef __attribute__((ext_vector_type(2))) _Float16 f16x2;
typedef __attribute__((ext_vector_type(4))) float   f32x4;

__device__ __forceinline__ float lrelu(float x) { return x > 0.f ? x : 0.01f * x; }
__device__ __forceinline__ float sigm(float x)  { return 1.f / (1.f + __expf(-x)); }
__device__ __forceinline__ f32x4 MFH(f16x8 a, f16x8 b, f32x4 c) {
  return __builtin_amdgcn_mfma_f32_16x16x32_f16(a, b, c, 0, 0, 0);
}

// ---------------------------------------------------------------- lin0 (LDS-staged weights)
__global__ __launch_bounds__(256) void lin0_kernel(const float* __restrict__ x,
                            const float* __restrict__ w, const float* __restrict__ b,
                            float* __restrict__ nodeF) {
  __shared__ float ws[64 * 15];
  __shared__ float bs[64];
  __shared__ float xr[4][16];
  const int tid = threadIdx.x;
  for (int i = tid; i < 896; i += 256) { int o = i / 14, j = i % 14; ws[o * 15 + j] = w[i]; }
  if (tid < 64) bs[tid] = b[tid];
  const int nl = tid >> 6, o = tid & 63;
  const int n = blockIdx.x * 4 + nl;
  if (o < 14 && n < N_NODES_C) xr[nl][o] = x[n * 14 + o];
  __syncthreads();
  if (n < N_NODES_C) {
    float s = bs[o];
#pragma unroll
    for (int j = 0; j < 14; ++j) s += xr[nl][j] * ws[o * 15 + j];
    nodeF[n * 64 + o] = lrelu(s);
  }
}

// ---------------------------------------------------------------- degree + graph offsets (merged)
__global__ void deg_kernel(const int* __restrict__ ei, const int* __restrict__ batch,
                           float* __restrict__ deg, int* __restrict__ goff) {
  int e = blockIdx.x * blockDim.x + threadIdx.x;
  if (e < N_EDGES_C) atomicAdd(&deg[ei[N_EDGES_C + e]], 1.f);
  if (e <= N_GRAPHS_C) {
    int lo = 0, hi = N_NODES_C;
    while (lo < hi) { int mid = (lo + hi) >> 1; if (batch[mid] < e) lo = mid + 1; else hi = mid; }
    goff[e] = lo;
  }
}

__global__ void invdeg_kernel(float* __restrict__ deg) {
  int n = blockIdx.x * blockDim.x + threadIdx.x;
  if (n < N_NODES_C) { float v = deg[n]; deg[n] = v > 0.f ? 1.f / v : 0.f; }
}

// ---------------------------------------------------------------- all weight prep (merged)
// Wp[i]: i = ((((d*2+oh)*2+p)*4 + q)*64 + lane)*8 + j ; q = kci*2+ob
//   o = oh*32+ob*16+(lane&15), h = (p*2+kci)*32+(lane>>4)*8+j, value = W2[(d*64+o)*128+h]
// B2p[i]: i = (((oh*2+ob)*2+kc2)*64+lane)*8+j ; o as above, d = kc2*32+(lane>>4)*8+j
__global__ __launch_bounds__(256) void prep_kernel(
    const float* __restrict__ net_w2, const float* __restrict__ net_b2,
    const float* __restrict__ conv_root,
    const float* __restrict__ w_ih, const float* __restrict__ w_hh,
    _Float16* __restrict__ Wp, _Float16* __restrict__ B2p,
    _Float16* __restrict__ Rtp, _Float16* __restrict__ Wip, _Float16* __restrict__ Whp) {
  int i = blockIdx.x * 256 + threadIdx.x;  // < 524288
  {
    int j = i & 7, lane = (i >> 3) & 63, q = (i >> 9) & 3, p = (i >> 11) & 1;
    int oh = (i >> 12) & 1, d = i >> 13;
    int kci = q >> 1, ob = q & 1;
    int col = lane & 15, kg = lane >> 4;
    int o = oh * 32 + ob * 16 + col, h = (p * 2 + kci) * 32 + kg * 8 + j;
    Wp[i] = (_Float16)net_w2[((size_t)d * 64 + o) * 128 + h];
  }
  if (i < 4096) {
    int j = i & 7, lane = (i >> 3) & 63, kc2 = (i >> 9) & 1, ob = (i >> 10) & 1, oh = (i >> 11) & 1;
    int col = lane & 15, kg = lane >> 4;
    int o = oh * 32 + ob * 16 + col, d = kc2 * 32 + kg * 8 + j;
    B2p[i] = (_Float16)net_b2[d * 64 + o];
  }
  if (i < 12288) {
    int j = i & 7, lane = (i >> 3) & 63, kc = (i >> 9) & 1, t = i >> 10;
    int o = t * 16 + (lane & 15), d = kc * 32 + (lane >> 4) * 8 + j;
    if (i < 4096) Rtp[i] = (_Float16)conv_root[d * 64 + o];  // B[o,d] = root[d,o]
    Wip[i] = (_Float16)w_ih[o * 64 + d];
    Whp[i] = (_Float16)w_hh[o * 64 + d];
  }
}

// ---------------------------------------------------------------- NNConv message + scatter
// (R12/R15 form: wave tile 64e x 32o; counted vmcnt(4) + sched_barrier, depth-2)
__global__ __launch_bounds__(256, 3) void msg_kernel(
    const float* __restrict__ nodef,     // [N,64]
    const int*   __restrict__ ei,        // [2,E]
    const float* __restrict__ eattr,     // [E,4]
    const float* __restrict__ net_w1,    // [128,4]
    const float* __restrict__ net_b1,    // [128]
    const _Float16* __restrict__ Wp,     // frag-major W2 fp16 (1 MB)
    const _Float16* __restrict__ B2p,    // frag-major b2 fp16 (8 KB)
    float* __restrict__ aggr)            // [N,64]
{
  __shared__ _Float16 xsT[EPB * 64];   // 16 KB  xsT[e][d ^ ((e&7)<<3)]
  __shared__ float    w1s[128 * 5];    // 2.5 KB (w0..w3, b1) per hidden unit

  const int tid = threadIdx.x;         // 0..255
  const int e0 = blockIdx.x * EPB;

  if (tid < 128) {
    float4 wv = *(const float4*)(net_w1 + tid * 4);
    w1s[tid * 5 + 0] = wv.x; w1s[tid * 5 + 1] = wv.y;
    w1s[tid * 5 + 2] = wv.z; w1s[tid * 5 + 3] = wv.w;
    w1s[tid * 5 + 4] = net_b1[tid];
  }
  {
    const int e = tid >> 1, dh = (tid & 1) * 32;
    int ge = e0 + e;
    const int esw = (e & 7) << 3;
#pragma unroll
    for (int jb = 0; jb < 4; ++jb) {
      int d = dh + jb * 8;
      float4 v0, v1;
      if (ge < N_EDGES_C) {
        const float4* nf4 = (const float4*)(nodef + (size_t)ei[ge] * 64 + d);
        v0 = nf4[0]; v1 = nf4[1];
      } else {
        v0 = make_float4(0.f, 0.f, 0.f, 0.f); v1 = v0;
      }
      f16x8 pk;
      pk[0] = (_Float16)v0.x; pk[1] = (_Float16)v0.y; pk[2] = (_Float16)v0.z; pk[3] = (_Float16)v0.w;
      pk[4] = (_Float16)v1.x; pk[5] = (_Float16)v1.y; pk[6] = (_Float16)v1.z; pk[7] = (_Float16)v1.w;
      *(f16x8*)&xsT[e * 64 + (d ^ esw)] = pk;
    }
  }

  const int lane = tid & 63, wv = tid >> 6;
  const int e0w = (wv & 1) * 64;
  const int oh  = wv >> 1;
  const int col = lane & 15;
  const int kg  = lane >> 4;
  const int swz = (col & 7) << 3;

  __syncthreads();

  f32x4 acc[4][2];
#pragma unroll
  for (int eb = 0; eb < 4; ++eb) { acc[eb][0] = 0.f; acc[eb][1] = 0.f; }
#pragma unroll
  for (int ob = 0; ob < 2; ++ob)
#pragma unroll
    for (int kc2 = 0; kc2 < 2; ++kc2) {
      f16x8 b2f = *(const f16x8*)(B2p + oh * 2048 + ob * 1024 + kc2 * 512 + lane * 8);
#pragma unroll
      for (int eb = 0; eb < 4; ++eb) {
        f16x8 xf = *(const f16x8*)&xsT[(e0w + eb * 16 + col) * 64 + ((kc2 * 32 + kg * 8) ^ swz)];
        acc[eb][ob] = MFH(xf, b2f, acc[eb][ob]);
      }
    }

  float4 at[4];
#pragma unroll
  for (int eb = 0; eb < 4; ++eb) {
    int ge = e0 + e0w + eb * 16 + col;
    at[eb] = (ge < N_EDGES_C) ? *(const float4*)(eattr + (size_t)ge * 4)
                              : make_float4(0.f, 0.f, 0.f, 0.f);
  }

#define ISSUE(BUF, ADDR)                                                  \
  asm volatile("global_load_dwordx4 %0, %4, off\n\t"                      \
               "global_load_dwordx4 %1, %4, off offset:1024\n\t"          \
               "global_load_dwordx4 %2, %4, off offset:2048\n\t"          \
               "global_load_dwordx4 %3, %4, off offset:3072"              \
               : "=&v"(BUF[0]), "=&v"(BUF[1]), "=&v"(BUF[2]), "=&v"(BUF[3]) \
               : "v"(ADDR)                                                \
               : "memory")
#define COMPUTE(BUF, XV, J)                                               \
  {                                                                       \
    _Pragma("unroll")                                                     \
    for (int eb = 0; eb < 4; ++eb) {                                      \
      unsigned dw = XV[eb].u[(J) >> 1];                                   \
      unsigned xd = __builtin_amdgcn_perm(dw, dw, ((J) & 1) ? 0x03020302u : 0x01000100u); \
      f16x2 x2; { union { unsigned u; f16x2 h; } c; c.u = xd; x2 = c.h; } \
      _Pragma("unroll")                                                   \
      for (int kci = 0; kci < 2; ++kci) {                                 \
        union { f16x8 v; f16x2 pp[4]; } af, Uu;                           \
        af.v = Af[eb][kci];                                               \
        _Pragma("unroll")                                                 \
        for (int q = 0; q < 4; ++q) Uu.pp[q] = af.pp[q] * x2;             \
        acc[eb][0] = MFH(Uu.v, BUF[kci * 2 + 0], acc[eb][0]);             \
        acc[eb][1] = MFH(Uu.v, BUF[kci * 2 + 1], acc[eb][1]);             \
      }                                                                   \
    }                                                                     \
  }

  const _Float16* wp_base = Wp + oh * 4096 + lane * 8;
#pragma unroll 1
  for (int p = 0; p < 2; ++p) {
    f16x8 Af[4][2];
#pragma unroll
    for (int kci = 0; kci < 2; ++kci) {
      float4 wr[8]; float wb[8];
#pragma unroll
      for (int j = 0; j < 8; ++j) {
        int hq = (p * 2 + kci) * 32 + kg * 8 + j;
        wr[j] = *(const float4*)&w1s[hq * 5];
        wb[j] = w1s[hq * 5 + 4];
      }
#pragma unroll
      for (int eb = 0; eb < 4; ++eb) {
        f16x8 F;
#pragma unroll
        for (int j = 0; j < 8; ++j) {
          float a = wb[j] + at[eb].x * wr[j].x + at[eb].y * wr[j].y
                          + at[eb].z * wr[j].z + at[eb].w * wr[j].w;
          F[j] = (_Float16)lrelu(a);
        }
        Af[eb][kci] = F;
      }
    }

    const _Float16* wp_p = wp_base + p * 2048;
    f16x8 B0[4], B1[4];
    ISSUE(B0, wp_p);
    ISSUE(B1, wp_p + 8192);

#pragma unroll 1
    for (int d8 = 0; d8 < 64; d8 += 8) {
      union XU { f16x8 v; unsigned u[4]; };
      XU XV[4];
#pragma unroll
      for (int eb = 0; eb < 4; ++eb)
        XV[eb].v = *(const f16x8*)&xsT[(e0w + eb * 16 + col) * 64 + (d8 ^ swz)];
#pragma unroll
      for (int j = 0; j < 8; ++j) {
        const int d = d8 + j;
        if (d < 63) { asm volatile("s_waitcnt vmcnt(4)"); }
        else        { asm volatile("s_waitcnt vmcnt(0)"); }
        __builtin_amdgcn_sched_barrier(0);
        if ((j & 1) == 0) { COMPUTE(B0, XV, j); } else { COMPUTE(B1, XV, j); }
        __builtin_amdgcn_sched_barrier(0);
        if (d < 62) {
          const _Float16* adr = wp_p + (size_t)(d + 2) * 8192;
          if ((j & 1) == 0) { ISSUE(B0, adr); } else { ISSUE(B1, adr); }
        }
      }
    }
  }
#undef ISSUE
#undef COMPUTE

  const int o0w = oh * 32;
#pragma unroll
  for (int eb = 0; eb < 4; ++eb) {
#pragma unroll
    for (int r = 0; r < 4; ++r) {
      int e = e0w + eb * 16 + kg * 4 + r;
      int ge = e0 + e;
      if (ge < N_EDGES_C) {
        int dn = ei[N_EDGES_C + ge];
        atomicAdd(&aggr[(size_t)dn * 64 + o0w + col],      acc[eb][0][r]);
        atomicAdd(&aggr[(size_t)dn * 64 + o0w + 16 + col], acc[eb][1][r]);
      }
    }
  }
}

// ---------------------------------------------------------------- root matmul + GRU (fp16 MFMA)
// Block: 32 nodes, 2 waves x 16 nodes; aggr reads hoisted before Phase-1 MFMA.
__global__ __launch_bounds__(128) void node_update_kernel(
    float* __restrict__ aggr, const float* __restrict__ invdeg,
    const _Float16* __restrict__ Rtp, const _Float16* __restrict__ Wip,
    const _Float16* __restrict__ Whp,
    const float* __restrict__ conv_bias,
    const float* __restrict__ b_ih, const float* __restrict__ b_hh,
    float* __restrict__ nodeF)
{
  __shared__ _Float16 ms[2][16 * 64];

  const int tid = threadIdx.x, lane = tid & 63, wv = tid >> 6;
  const int col = lane & 15, kg = lane >> 4;
  const int nwb = blockIdx.x * 32 + wv * 16;

  float invd[4]; int nrow[4];
#pragma unroll
  for (int r = 0; r < 4; ++r) {
    int nn = nwb + kg * 4 + r; nrow[r] = nn;
    invd[r] = (nn < N_NODES_C) ? invdeg[nn] : 0.f;
  }
  float ag[4][4];
#pragma unroll
  for (int t = 0; t < 4; ++t)
#pragma unroll
    for (int r = 0; r < 4; ++r) {
      int nn = nrow[r];
      ag[t][r] = (nn < N_NODES_C) ? aggr[(size_t)nn * 64 + t * 16 + col] : 0.f;
    }

  int arow = nwb + col; if (arow >= N_NODES_C) arow = N_NODES_C - 1;
  f16x8 nf[2];
#pragma unroll
  for (int kc = 0; kc < 2; ++kc) {
    f32x4 v0 = *(const f32x4*)(nodeF + (size_t)arow * 64 + kc * 32 + kg * 8);
    f32x4 v1 = *(const f32x4*)(nodeF + (size_t)arow * 64 + kc * 32 + kg * 8 + 4);
    f16x8 F;
#pragma unroll
    for (int j = 0; j < 4; ++j) { F[j] = (_Float16)v0[j]; F[4 + j] = (_Float16)v1[j]; }
    nf[kc] = F;
  }

  f32x4 racc[4];
#pragma unroll
  for (int t = 0; t < 4; ++t) racc[t] = conv_bias[t * 16 + col];
#pragma unroll
  for (int t = 0; t < 4; ++t)
#pragma unroll
    for (int kc = 0; kc < 2; ++kc)
      racc[t] = MFH(nf[kc], *(const f16x8*)(Rtp + t * 1024 + kc * 512 + lane * 8), racc[t]);

#pragma unroll
  for (int t = 0; t < 4; ++t) {
#pragma unroll
    for (int r = 0; r < 4; ++r) {
      int nn = nrow[r];
      if (nn < N_NODES_C) aggr[(size_t)nn * 64 + t * 16 + col] = 0.f;  // re-zero
      float mval = lrelu(ag[t][r] * invd[r] + racc[t][r]);
      int nl = kg * 4 + r;
      int dsw = (t * 16 + col) ^ ((nl & 7) << 3);
      ms[wv][nl * 64 + dsw] = (_Float16)mval;
    }
  }
  __syncthreads();

  f16x8 ma[2];
#pragma unroll
  for (int kc = 0; kc < 2; ++kc)
    ma[kc] = *(const f16x8*)&ms[wv][col * 64 + ((kc * 32 + kg * 8) ^ ((col & 7) << 3))];

  f32x4 gi[12], gh[12];
#pragma unroll
  for (int t = 0; t < 12; ++t) { gi[t] = b_ih[t * 16 + col]; gh[t] = b_hh[t * 16 + col]; }
#pragma unroll
  for (int t = 0; t < 12; ++t)
#pragma unroll
    for (int kc = 0; kc < 2; ++kc) {
      gi[t] = MFH(ma[kc], *(const f16x8*)(Wip + t * 1024 + kc * 512 + lane * 8), gi[t]);
      gh[t] = MFH(nf[kc], *(const f16x8*)(Whp + t * 1024 + kc * 512 + lane * 8), gh[t]);
    }

#pragma unroll
  for (int t = 0; t < 4; ++t) {
#pragma unroll
    for (int r = 0; r < 4; ++r) {
      int nn = nrow[r];
      if (nn >= N_NODES_C) continue;
      size_t idx = (size_t)nn * 64 + t * 16 + col;
      float hv = nodeF[idx];
      float rr = sigm(gi[t][r] + gh[t][r]);
      float zz = sigm(gi[t + 4][r] + gh[t + 4][r]);
      float nv = tanhf(gi[t + 8][r] + rr * gh[t + 8][r]);
      nodeF[idx] = (1.f - zz) * nv + zz * hv;
    }
  }
}

// ---------------------------------------------------------------- fused Set2Set (3 steps) + final linear
// 256 threads: LSTM gate-per-thread, attention 4 rows/iter.
__global__ __launch_bounds__(256) void set2set_kernel(
    const float* __restrict__ nodeF, const int* __restrict__ goff,
    const float* __restrict__ w_ih, const float* __restrict__ w_hh,
    const float* __restrict__ b_ih, const float* __restrict__ b_hh,
    const float* __restrict__ lw, const float* __restrict__ lb,
    float* __restrict__ ebuf, float* __restrict__ dout)
{
  const int g = blockIdx.x, tid = threadIdx.x;
  const int t = tid & 63, grp = tid >> 6;
  __shared__ float qs[128], hs[64], cls[64], gvs[4][64], red[4][64], scal[8];
  if (tid < 128) qs[tid] = 0.f;
  if (tid < 64) { hs[tid] = 0.f; cls[tid] = 0.f; }
  const int s0 = goff[g], s1 = goff[g + 1];
  __syncthreads();

  for (int step = 0; step < 3; ++step) {
    {
      float s = b_ih[grp * 64 + t] + b_hh[grp * 64 + t];
      const float4* wi4 = (const float4*)(w_ih + (grp * 64 + t) * 128);
#pragma unroll 8
      for (int j = 0; j < 32; ++j) {
        float4 w = wi4[j];
        s += qs[4 * j] * w.x + qs[4 * j + 1] * w.y + qs[4 * j + 2] * w.z + qs[4 * j + 3] * w.w;
      }
      const float4* wh4 = (const float4*)(w_hh + (grp * 64 + t) * 64);
#pragma unroll 8
      for (int j = 0; j < 16; ++j) {
        float4 w = wh4[j];
        s += hs[4 * j] * w.x + hs[4 * j + 1] * w.y + hs[4 * j + 2] * w.z + hs[4 * j + 3] * w.w;
      }
      gvs[grp][t] = s;
    }
    __syncthreads();
    if (tid < 64) {
      float c = sigm(gvs[1][t]) * cls[t] + sigm(gvs[0][t]) * tanhf(gvs[2][t]);
      float hn = sigm(gvs[3][t]) * tanhf(c);
      cls[t] = c; hs[t] = hn; qs[t] = hn;
    }
    __syncthreads();
    const float qv = hs[t];

    float emax = -3.0e38f;
    for (int n = s0 + grp; n < s1; n += 4) {
      float p = nodeF[(size_t)n * 64 + t] * qv;
#pragma unroll
      for (int off = 32; off > 0; off >>= 1) p += __shfl_down(p, off);
      float en = __shfl(p, 0);
      if (t == 0) ebuf[n] = en;
      emax = fmaxf(emax, en);
    }
    if (t == 0) scal[grp] = emax;
    __syncthreads();
    emax = fmaxf(fmaxf(scal[0], scal[1]), fmaxf(scal[2], scal[3]));

    float lsum = 0.f;
    for (int n = s0 + tid; n < s1; n += 256) {
      float ex = __expf(ebuf[n] - emax);
      ebuf[n] = ex;
      lsum += ex;
    }
#pragma unroll
    for (int off = 32; off > 0; off >>= 1) lsum += __shfl_down(lsum, off);
    if (t == 0) scal[4 + grp] = lsum;
    __syncthreads();
    float denom = scal[4] + scal[5] + scal[6] + scal[7];

    float r = 0.f;
    for (int n = s0 + grp; n < s1; n += 4) r += ebuf[n] * nodeF[(size_t)n * 64 + t];
    red[grp][t] = r;
    __syncthreads();
    if (tid < 64) {
      float rr = red[0][t] + red[1][t] + red[2][t] + red[3][t];
      qs[64 + t] = (s1 > s0) ? rr / denom : 0.f;
    }
    __syncthreads();
  }
  float sacc = (tid < 128) ? qs[tid] * lw[tid] : 0.f;
#pragma unroll
  for (int off = 32; off > 0; off >>= 1) sacc += __shfl_down(sacc, off);
  if (t == 0) scal[grp] = sacc;
  __syncthreads();
  if (tid == 0) dout[g] = scal[0] + scal[1] + lb[0];
}

// ---------------------------------------------------------------- launch
extern "C" void kernel_launch(void* const* d_in, const int* in_sizes, int n_in,
                              void* d_out, int out_size, void* d_ws, size_t ws_size,
                              hipStream_t stream) {
  const float* x         = (const float*)d_in[0];
  const int*   ei        = (const int*)  d_in[1];
  const float* eattr     = (const float*)d_in[2];
  const int*   batch     = (const int*)  d_in[3];
  const float* lin0_w    = (const float*)d_in[4];
  const float* lin0_b    = (const float*)d_in[5];
  const float* net_w1    = (const float*)d_in[6];
  const float* net_b1    = (const float*)d_in[7];
  const float* net_w2    = (const float*)d_in[8];
  const float* net_b2    = (const float*)d_in[9];
  const float* conv_root = (const float*)d_in[10];
  const float* conv_bias = (const float*)d_in[11];
  const float* gru_w_ih  = (const float*)d_in[12];
  const float* gru_w_hh  = (const float*)d_in[13];
  const float* gru_b_ih  = (const float*)d_in[14];
  const float* gru_b_hh  = (const float*)d_in[15];
  const float* lstm_w_ih = (const float*)d_in[16];
  const float* lstm_w_hh = (const float*)d_in[17];
  const float* lstm_b_ih = (const float*)d_in[18];
  const float* lstm_b_hh = (const float*)d_in[19];
  const float* lin_w     = (const float*)d_in[20];
  const float* lin_b     = (const float*)d_in[21];

  // workspace layout (~13.1 MB)
  float* ws    = (float*)d_ws;
  float* nodeF = ws;                         // 1,600,000 f
  float* aggr  = nodeF + 1600000;            // 1,600,000 f
  float* deg   = aggr + 1600000;             //    25,000 f
  float* ebuf  = deg + 25000;                //    25,000 f
  int*   goff  = (int*)(ebuf + 25000);       //     1,024 i
  _Float16* Rtp = (_Float16*)(goff + 1024);  //     4,096 h
  _Float16* Wip = Rtp + 4096;                //    12,288 h
  _Float16* Whp = Wip + 12288;               //    12,288 h
  _Float16* Wp  = Whp + 12288;               //   524,288 h
  _Float16* B2p = Wp + 524288;               //     4,096 h

  hipMemsetAsync(deg, 0, 25000 * sizeof(float), stream);
  hipMemsetAsync(aggr, 0, 1600000 * sizeof(float), stream);  // node_update re-zeroes thereafter

  lin0_kernel<<<(N_NODES_C + 3) / 4, 256, 0, stream>>>(x, lin0_w, lin0_b, nodeF);
  deg_kernel<<<(N_EDGES_C + 255) / 256, 256, 0, stream>>>(ei, batch, deg, goff);
  invdeg_kernel<<<(N_NODES_C + 255) / 256, 256, 0, stream>>>(deg);
  prep_kernel<<<2048, 256, 0, stream>>>(net_w2, net_b2, conv_root, gru_w_ih, gru_w_hh,
                                        Wp, B2p, Rtp, Wip, Whp);

  for (int step = 0; step < 3; ++step) {
    msg_kernel<<<(N_EDGES_C + EPB - 1) / EPB, 256, 0, stream>>>(
        nodeF, ei, eattr, net_w1, net_b1, Wp, B2p, aggr);
    node_update_kernel<<<(N_NODES_C + 31) / 32, 128, 0, stream>>>(
        aggr, deg, Rtp, Wip, Whp, conv_bias, gru_b_ih, gru_b_hh, nodeF);
  }

  set2set_kernel<<<N_GRAPHS_C, 256, 0, stream>>>(
      nodeF, goff, lstm_w_ih, lstm_w_hh, lstm_b_ih, lstm_b_hh, lin_w, lin_b, ebuf, (float*)d_out);
}